// Round 1
// 61397.363 us; speedup vs baseline: 1.2513x; 1.2513x over previous
//
#include <hip/hip_runtime.h>

#define HD 1024
#define BAT 64
#define KC 128
#define TT 512
#define II 256

typedef unsigned short u16;
typedef unsigned int u32;

__device__ __forceinline__ float bf2f(u16 v) {
    return __uint_as_float(((u32)v) << 16);
}

__device__ __forceinline__ u16 f2bf(float f) {
    u32 u = __float_as_uint(f);
    u32 lsb = (u >> 16) & 1u;
    u += 0x7FFFu + lsb;          // round-to-nearest-even
    return (u16)(u >> 16);
}

__device__ __forceinline__ void unpack8(const uint4 v, float* dst) {
    dst[0] = __uint_as_float(v.x << 16);
    dst[1] = __uint_as_float(v.x & 0xFFFF0000u);
    dst[2] = __uint_as_float(v.y << 16);
    dst[3] = __uint_as_float(v.y & 0xFFFF0000u);
    dst[4] = __uint_as_float(v.z << 16);
    dst[5] = __uint_as_float(v.z & 0xFFFF0000u);
    dst[6] = __uint_as_float(v.w << 16);
    dst[7] = __uint_as_float(v.w & 0xFFFF0000u);
}

// flag=1 if external tensors are bf16, 0 if fp32.
__global__ void detect_dtype(const u16* __restrict__ x, int* __restrict__ flag) {
    u32 u = x[(threadIdx.x & 63) * 2];
    u32 e = (u >> 7) & 0xFFu;
    bool sane = (e >= 0x60u) && (e <= 0x9Fu);
    unsigned long long m = __ballot(sane);
    if (threadIdx.x == 0) flag[0] = (__popcll(m) >= 48) ? 1 : 0;
}

// Skewed dual-layer LSTM step. grid = 512: blocks [0,256) run layer0 step t,
// blocks [256,512) run layer1 step t-1 (disjoint buffers -> no intra-launch dep).
// block = 256 thr = 4 waves; wave owns unit n = bn + wave; lane = batch.
// fp32 path: software-pipelined staging (issue next chunk's global loads to regs
// during current chunk's FMA; write regs->LDS after the barrier).
__global__ __launch_bounds__(256) void lstm_step2(
    const int* __restrict__ flag, int t,
    const void* __restrict__ x,
    const void* __restrict__ Wih0, const void* __restrict__ Whh0,
    const void* __restrict__ bih0, const void* __restrict__ bhh0,
    float* __restrict__ c1, const float* __restrict__ h1_prev, float* __restrict__ h1_out,
    const void* __restrict__ Wih1, const void* __restrict__ Whh1,
    const void* __restrict__ bih1, const void* __restrict__ bhh1,
    float* __restrict__ c2, const float* __restrict__ h2_prev, float* __restrict__ h2_out)
{
    __shared__ __align__(16) float As[BAT * 132];
    __shared__ __align__(16) float Ws[16 * 132];

    const int layer = blockIdx.x >> 8;
    if (layer == 0) { if (t == TT) return; }   // drain launch: layer0 idle
    else           { if (t == 0)  return; }    // fill launch: layer1 idle

    const int tid  = threadIdx.x;
    const int wave = tid >> 6;
    const int lane = tid & 63;
    const int bn   = (blockIdx.x & 255) * 4;
    const int n    = bn + wave;
    const int bf   = flag[0];

    // per-layer parameter selection
    const void *A1, *Wih, *Whh, *bi, *bh;
    const float* hprev; float *cst, *hout;
    long long a1s, eoff; int K1, a1ext;
    if (layer == 0) {
        A1 = x; a1s = (long long)TT * II; eoff = (long long)t * II; K1 = II; a1ext = 1;
        Wih = Wih0; Whh = Whh0; bi = bih0; bh = bhh0;
        cst = c1; hprev = h1_prev; hout = h1_out;
    } else {
        // layer1 computes step s = t-1; h1[s] lives in h1_prev (written at launch t-1)
        A1 = h1_prev; a1s = (long long)HD; eoff = 0; K1 = HD; a1ext = 0;
        Wih = Wih1; Whh = Whh1; bi = bih1; bh = bhh1;
        cst = c2; hprev = h2_prev; hout = h2_out;
    }

    float acc0, acc1, acc2, acc3;
    if (bf) {
        const u16* bip = (const u16*)bi;
        const u16* bhp = (const u16*)bh;
        acc0 = bf2f(bip[n])        + bf2f(bhp[n]);
        acc1 = bf2f(bip[n + HD])   + bf2f(bhp[n + HD]);
        acc2 = bf2f(bip[n + 2*HD]) + bf2f(bhp[n + 2*HD]);
        acc3 = bf2f(bip[n + 3*HD]) + bf2f(bhp[n + 3*HD]);
    } else {
        const float* bip = (const float*)bi;
        const float* bhp = (const float*)bh;
        acc0 = bip[n]        + bhp[n];
        acc1 = bip[n + HD]   + bhp[n + HD];
        acc2 = bip[n + 2*HD] + bhp[n + 2*HD];
        acc3 = bip[n + 3*HD] + bhp[n + 3*HD];
    }

    if (!bf) {
        // ---------------- fast fp32 path: unified virtual-K loop + prefetch ----------------
        const float* A1f  = (const float*)A1;
        const float* Wihf = (const float*)Wih;
        const float* Whhf = (const float*)Whh;
        const int c0n = K1 >> 7;            // A1 chunks
        const int nch = c0n + (HD >> 7);    // total chunks

        float4 pa[8];   // staged A: 4 slots x 8 floats per thread
        float4 pw[2];   // staged W: 8 floats per thread

        auto issue = [&](int c) {
            const float* Ap; long long astr, aof; const float* Wp; long long wstr; int k0;
            if (c < c0n) { Ap = A1f;   astr = a1s; aof = eoff; Wp = Wihf; wstr = K1; k0 = c << 7; }
            else         { Ap = hprev; astr = HD;  aof = 0;    Wp = Whhf; wstr = HD; k0 = (c - c0n) << 7; }
            #pragma unroll
            for (int it = 0; it < 4; ++it) {
                int idx = it * 256 + tid;
                int r = idx >> 4, g = idx & 15;
                const float* p = Ap + (long long)r * astr + aof + k0 + g * 8;
                pa[2*it]   = *(const float4*)p;
                pa[2*it+1] = *(const float4*)(p + 4);
            }
            {
                int r = tid >> 4, g = tid & 15;
                long long row = (long long)((r & 3) * HD + bn + (r >> 2));
                const float* p = Wp + row * wstr + k0 + g * 8;
                pw[0] = *(const float4*)p;
                pw[1] = *(const float4*)(p + 4);
            }
        };

        issue(0);
        for (int c = 0; c < nch; ++c) {
            __syncthreads();                       // prev chunk's compute done; LDS free
            #pragma unroll
            for (int it = 0; it < 4; ++it) {       // regs -> LDS (waits vmcnt implicitly)
                int idx = it * 256 + tid;
                int r = idx >> 4, g = idx & 15;
                float* d = &As[r * 132 + g * 8];
                *(float4*)d       = pa[2*it];
                *(float4*)(d + 4) = pa[2*it+1];
            }
            {
                int r = tid >> 4, g = tid & 15;
                float* d = &Ws[r * 132 + g * 8];
                *(float4*)d       = pw[0];
                *(float4*)(d + 4) = pw[1];
            }
            __syncthreads();
            if (c + 1 < nch) issue(c + 1);         // loads fly during the FMA loop below

            const float* ap  = &As[lane * 132];
            const float* w0p = &Ws[(wave * 4 + 0) * 132];
            const float* w1p = &Ws[(wave * 4 + 1) * 132];
            const float* w2p = &Ws[(wave * 4 + 2) * 132];
            const float* w3p = &Ws[(wave * 4 + 3) * 132];
            #pragma unroll
            for (int kk = 0; kk < KC; kk += 4) {
                float4 a  = *(const float4*)(ap  + kk);
                float4 w0 = *(const float4*)(w0p + kk);
                float4 w1 = *(const float4*)(w1p + kk);
                float4 w2 = *(const float4*)(w2p + kk);
                float4 w3 = *(const float4*)(w3p + kk);
                acc0 = fmaf(a.x, w0.x, acc0); acc0 = fmaf(a.y, w0.y, acc0);
                acc0 = fmaf(a.z, w0.z, acc0); acc0 = fmaf(a.w, w0.w, acc0);
                acc1 = fmaf(a.x, w1.x, acc1); acc1 = fmaf(a.y, w1.y, acc1);
                acc1 = fmaf(a.z, w1.z, acc1); acc1 = fmaf(a.w, w1.w, acc1);
                acc2 = fmaf(a.x, w2.x, acc2); acc2 = fmaf(a.y, w2.y, acc2);
                acc2 = fmaf(a.z, w2.z, acc2); acc2 = fmaf(a.w, w2.w, acc2);
                acc3 = fmaf(a.x, w3.x, acc3); acc3 = fmaf(a.y, w3.y, acc3);
                acc3 = fmaf(a.z, w3.z, acc3); acc3 = fmaf(a.w, w3.w, acc3);
            }
        }
    } else {
        // ---------------- legacy path (bf16 external tensors), verbatim structure ----------------
        for (int phase = 0; phase < 2; ++phase) {
            const void* Am       = phase ? (const void*)hprev : A1;
            const long long astr = phase ? (long long)HD : a1s;
            const long long aoff = phase ? 0ll : eoff;
            const void* W        = phase ? Whh : Wih;
            const int K          = phase ? HD : K1;
            const int a_bf       = phase ? 0 : (a1ext & bf);

            for (int k0 = 0; k0 < K; k0 += KC) {
                if (a_bf) {
                    #pragma unroll
                    for (int it = 0; it < 4; ++it) {
                        int idx = it * 256 + tid;
                        int r = idx >> 4, g = idx & 15;
                        uint4 v = *(const uint4*)((const u16*)Am + (long long)r * astr + aoff + k0 + g * 8);
                        unpack8(v, &As[r * 132 + g * 8]);
                    }
                } else {
                    #pragma unroll
                    for (int it = 0; it < 4; ++it) {
                        int idx = it * 256 + tid;
                        int r = idx >> 4, g = idx & 15;
                        const float* p = (const float*)Am + (long long)r * astr + aoff + k0 + g * 8;
                        float4 lo = *(const float4*)p;
                        float4 hi = *(const float4*)(p + 4);
                        float* d = &As[r * 132 + g * 8];
                        *(float4*)d = lo;
                        *(float4*)(d + 4) = hi;
                    }
                }
                {
                    int r = tid >> 4, g = tid & 15;
                    long long row = (long long)((r & 3) * HD + bn + (r >> 2));
                    uint4 v = *(const uint4*)((const u16*)W + row * K + k0 + g * 8);
                    unpack8(v, &Ws[r * 132 + g * 8]);
                }
                __syncthreads();

                const float* ap  = &As[lane * 132];
                const float* w0p = &Ws[(wave * 4 + 0) * 132];
                const float* w1p = &Ws[(wave * 4 + 1) * 132];
                const float* w2p = &Ws[(wave * 4 + 2) * 132];
                const float* w3p = &Ws[(wave * 4 + 3) * 132];
                #pragma unroll
                for (int kk = 0; kk < KC; kk += 4) {
                    float4 a  = *(const float4*)(ap  + kk);
                    float4 w0 = *(const float4*)(w0p + kk);
                    float4 w1 = *(const float4*)(w1p + kk);
                    float4 w2 = *(const float4*)(w2p + kk);
                    float4 w3 = *(const float4*)(w3p + kk);
                    acc0 = fmaf(a.x, w0.x, acc0); acc0 = fmaf(a.y, w0.y, acc0);
                    acc0 = fmaf(a.z, w0.z, acc0); acc0 = fmaf(a.w, w0.w, acc0);
                    acc1 = fmaf(a.x, w1.x, acc1); acc1 = fmaf(a.y, w1.y, acc1);
                    acc1 = fmaf(a.z, w1.z, acc1); acc1 = fmaf(a.w, w1.w, acc1);
                    acc2 = fmaf(a.x, w2.x, acc2); acc2 = fmaf(a.y, w2.y, acc2);
                    acc2 = fmaf(a.z, w2.z, acc2); acc2 = fmaf(a.w, w2.w, acc2);
                    acc3 = fmaf(a.x, w3.x, acc3); acc3 = fmaf(a.y, w3.y, acc3);
                    acc3 = fmaf(a.z, w3.z, acc3); acc3 = fmaf(a.w, w3.w, acc3);
                }
                __syncthreads();
            }
        }
    }

    float ig = 1.f / (1.f + __expf(-acc0));
    float fg = 1.f / (1.f + __expf(-acc1));
    float gg = tanhf(acc2);
    float og = 1.f / (1.f + __expf(-acc3));
    long long ci = (long long)lane * HD + n;
    float cn = fg * cst[ci] + ig * gg;
    cst[ci] = cn;
    hout[ci] = og * tanhf(cn);
}

__global__ __launch_bounds__(256) void fc_kernel(
    const int* __restrict__ flag,
    const float* __restrict__ h, const void* __restrict__ w,
    const void* __restrict__ b, void* __restrict__ out)
{
    int bf = flag[0];
    int bb = blockIdx.x;
    int o  = threadIdx.x;
    const float* hr = h + bb * HD;
    if (bf) {
        float acc = bf2f(((const u16*)b)[o]);
        const u16* wr = (const u16*)w + o * HD;
        for (int k = 0; k < HD; k += 8) {
            uint4 wv = *(const uint4*)(wr + k);
            float wa[8];
            unpack8(wv, wa);
            #pragma unroll
            for (int j = 0; j < 8; ++j) acc = fmaf(hr[k + j], wa[j], acc);
        }
        ((u16*)out)[bb * 256 + o] = f2bf(acc);
    } else {
        float acc = ((const float*)b)[o];
        const float* wr = (const float*)w + o * HD;
        for (int k = 0; k < HD; k += 4) {
            float4 wv = *(const float4*)(wr + k);
            acc = fmaf(hr[k + 0], wv.x, acc);
            acc = fmaf(hr[k + 1], wv.y, acc);
            acc = fmaf(hr[k + 2], wv.z, acc);
            acc = fmaf(hr[k + 3], wv.w, acc);
        }
        ((float*)out)[bb * 256 + o] = acc;
    }
}

extern "C" void kernel_launch(void* const* d_in, const int* in_sizes, int n_in,
                              void* d_out, int out_size, void* d_ws, size_t ws_size,
                              hipStream_t stream) {
    const void* x    = d_in[0];
    const void* Wih0 = d_in[1];
    const void* Whh0 = d_in[2];
    const void* bih0 = d_in[3];
    const void* bhh0 = d_in[4];
    const void* Wih1 = d_in[5];
    const void* Whh1 = d_in[6];
    const void* bih1 = d_in[7];
    const void* bhh1 = d_in[8];
    const void* fcw  = d_in[9];
    const void* fcb  = d_in[10];

    char* ws = (char*)d_ws;
    const size_t HB = (size_t)BAT * HD * 4;   // 256 KB fp32 state buffer
    int*   flag     = (int*)ws;
    float* h1buf[2] = { (float*)(ws + 4096),          (float*)(ws + 4096 + HB) };
    float* h2buf[2] = { (float*)(ws + 4096 + 2 * HB), (float*)(ws + 4096 + 3 * HB) };
    float* c1       = (float*)(ws + 4096 + 4 * HB);
    float* c2       = (float*)(ws + 4096 + 5 * HB);

    size_t needed = 4096 + 6 * HB;
    size_t zbytes = (ws_size < needed) ? ws_size : needed;
    hipMemsetAsync(d_ws, 0, zbytes, stream);

    detect_dtype<<<1, 64, 0, stream>>>((const u16*)x, flag);

    // Skewed pipeline: launch t runs layer0 step t and layer1 step t-1.
    // h1[t] lands in h1buf[(t+1)&1]; layer1 at launch t+1 reads it as h1_prev.
    // h2[s] lands in h2buf[(s+1)&1]; final h2[511] (t=512) -> h2buf[0].
    for (int t = 0; t <= TT; ++t) {
        lstm_step2<<<512, 256, 0, stream>>>(
            flag, t, x,
            Wih0, Whh0, bih0, bhh0, c1, h1buf[t & 1], h1buf[(t + 1) & 1],
            Wih1, Whh1, bih1, bhh1, c2, h2buf[(t + 1) & 1], h2buf[t & 1]);
    }
    fc_kernel<<<64, 256, 0, stream>>>(flag, h2buf[0], fcw, fcb, d_out);
}